// Round 3
// baseline (602.432 us; speedup 1.0000x reference)
//
#include <hip/hip_runtime.h>
#include <cstdint>
#include <cstddef>

typedef unsigned short u16;
typedef unsigned int u32;
typedef __attribute__((ext_vector_type(8))) __bf16 bf16x8;
typedef __attribute__((ext_vector_type(4))) float f32x4;
typedef __attribute__((ext_vector_type(8))) unsigned short u16x8;
typedef __attribute__((ext_vector_type(4))) unsigned short u16x4;

__device__ __forceinline__ u16 f2bf(float f) {
  union { float f; unsigned u; } v; v.f = f;
  unsigned r = v.u + 0x7fffu + ((v.u >> 16) & 1u);   // RNE
  return (u16)(r >> 16);
}
__device__ __forceinline__ float bf2f(u16 x) {
  union { float f; unsigned u; } v; v.u = ((unsigned)x) << 16;
  return v.f;
}
// pack two f32 -> two bf16 (RNE)
__device__ __forceinline__ u32 pk2(float a, float b) {
  union { float f; unsigned u; } x, y; x.f = a; y.f = b;
  unsigned ra = x.u + 0x7fffu + ((x.u >> 16) & 1u);
  unsigned rb = y.u + 0x7fffu + ((y.u >> 16) & 1u);
  return (ra >> 16) | (rb & 0xffff0000u);
}

__device__ __forceinline__ void gll16(const void* g, void* l) {
  __builtin_amdgcn_global_load_lds(
      (const __attribute__((address_space(1))) void*)g,
      (__attribute__((address_space(3))) void*)l, 16, 0, 0);
}

// ---------------------------------------------------------------------------
// x (f32) -> bf16
__global__ __launch_bounds__(256) void cvt_x(const float* __restrict__ x,
                                             u16* __restrict__ xb, int n) {
  int i = (blockIdx.x * 256 + threadIdx.x) * 4;
  if (i < n) {
    float4 v = *(const float4*)(x + i);
    u16x4 o = { f2bf(v.x), f2bf(v.y), f2bf(v.z), f2bf(v.w) };
    *(u16x4*)(xb + i) = o;
  }
}

// ---------------------------------------------------------------------------
// W3^T (3072 x 1024) bf16, with per-64-chunk column permutation baked in:
// physical row n holds LOGICAL column (n&~63) | lam(n&63), lam(u)=(u&15)*4+(u>>4).
__global__ __launch_bounds__(256) void build_w3t(const float* __restrict__ Wq,
                                                 const float* __restrict__ Wkv,
                                                 u16* __restrict__ W3t) {
  __shared__ float tile[32][33];
  int bx = blockIdx.x, by = blockIdx.y;          // bx: n-tile (96), by: k-tile (32)
  int tx = threadIdx.x & 31, tyb = threadIdx.x >> 5;
  int n = bx * 32 + tx;                          // physical row
  int u = n & 63;
  int nl = (n & ~63) | ((u & 15) << 2) | (u >> 4);  // logical column
  const float* src; int scol, sld;
  if (nl < 1024)      { src = Wq;  scol = nl;                                  sld = 1024; }
  else if (nl < 2048) { int m = nl - 1024; src = Wkv; scol = (m >> 6) * 128 + (m & 63);      sld = 2048; }
  else                { int m = nl - 2048; src = Wkv; scol = (m >> 6) * 128 + 64 + (m & 63); sld = 2048; }
#pragma unroll
  for (int i = 0; i < 4; ++i) {
    int k = by * 32 + tyb + i * 8;
    tile[tyb + i * 8][tx] = src[(size_t)k * sld + scol];
  }
  __syncthreads();
#pragma unroll
  for (int i = 0; i < 4; ++i) {
    int n2 = bx * 32 + tyb + i * 8;
    int k2 = by * 32 + tx;
    W3t[(size_t)n2 * 1024 + k2] = f2bf(tile[tx][tyb + i * 8]);
  }
}

// ---------------------------------------------------------------------------
// 256x256 bf16 GEMM, merged-region schedule: 3 barriers / K-tile (vs 8).
// 512 thr = 8 waves (2M x 4N), BK=64, LDS 128 KiB dbuf, counted vmcnt(6),
// XOR-swizzled LDS reads with pre-swizzled global staging (linear LDS dest).
//
// Per K-tile:
//   R1: issue 16 ds_reads (A-lo, B0, B1) + stage B1(t+1)->nbuf;
//       q1 (Alo x B0) [rb1 drains under it]; q2 (Alo x B1); BARRIER
//       (at barrier: every wave consumed rb0/rb1 -> all B reads drained)
//   R2: issue 8 ds_reads (A-hi, overwrites ra) + stage B0(t+2)->cur (B safe);
//       q3 (Ahi x B1); BARRIER (all A reads drained);
//       stage A0,A1(t+2)->cur; q4 (Ahi x B0, pure-register);
//       vmcnt(6) [tile t+1 landed, t+2's 6 in flight]; BARRIER
// Compiler inserts per-register lgkmcnt between ds_read and consuming MFMA
// (fine-grained, per m97 asm evidence) -> reads overlap MFMA windows.
//
// XCD 2D chunking: each XCD owns a (nby/4) x (nbx/2) tile rectangle,
// M-fastest walk -> L2 working set = 1 A panel + (nbx/2) B panels.
//
// MODE 1: epilogue QKV (Q: row-softmax*SCALE; K: exp + Z col-sums; V: raw) -> bf16 L
// MODE 2: f32 out + bias, Bt batched by tileM/rows_per_batch.
template <int MODE>
__global__ __launch_bounds__(512, 2)
void gemm_bt_k(const u16* __restrict__ A, int lda,
               const u16* __restrict__ Bt0, int ldb, int K,
               u16* __restrict__ Lout, int ldc,
               float* __restrict__ Fout,
               float* __restrict__ Zp, const float* __restrict__ bias,
               size_t bstride, int rows_per_batch) {
  __shared__ __align__(16) char sm[131072];   // [buf][A|B]: buf*65536 + ab*32768
  const int tid  = threadIdx.x;
  const int lane = tid & 63, w = tid >> 6;
  const int wm = w >> 2, wn = w & 3;

  // XCD-aware 2D chunk decode (requires nby%4==0, nbx%2==0, bijective)
  const int nbx = gridDim.x;                 // N tiles
  const int nby = gridDim.y;                 // M tiles
  const int o = blockIdx.y * nbx + blockIdx.x;
  const int x = o & 7, j = o >> 3;
  const int CM = nby >> 2, CN = nbx >> 1;    // chunk = CM x CN tiles
  const int jm = j % CM, jn = j / CM;        // M-fastest within chunk
  const int tileM = ((x >> 1) * CM + jm) * 256;
  const int tileN = ((x & 1) * CN + jn) * 256;

  const u16* Bt = Bt0;
  if (MODE == 2) Bt += (size_t)(tileM / rows_per_batch) * bstride;

  // ---- staging addressing (global source pre-swizzled, LDS dest linear) ----
  const int r0 = tid >> 3;                   // row within 64-row round
  const int pp = (tid & 7) ^ (r0 & 7);       // swizzled 16B chunk within 128B row
  const u16* gA = A  + (size_t)(tileM + r0) * lda + pp * 8;
  const u16* gB = Bt + (size_t)(tileN + r0) * ldb + pp * 8;
  char* smw = sm + w * 1024;                 // wave-uniform LDS base (round 0)

  // ---- ds_read addressing (swizzled) ----
  const int cl = lane & 15, q = lane >> 4;
  int roA[8], roB[4];
#pragma unroll
  for (int mi = 0; mi < 8; ++mi) roA[mi] = (wm * 128 + mi * 16 + cl) * 128;
#pragma unroll
  for (int ni = 0; ni < 4; ++ni) roB[ni] = (wn * 64 + ni * 16 + cl) * 128;
  const int ck0 = ((0 + q) ^ (cl & 7)) * 16;
  const int ck1 = ((4 + q) ^ (cl & 7)) * 16;

  f32x4 acc[8][4];
#pragma unroll
  for (int i = 0; i < 8; ++i)
#pragma unroll
    for (int j2 = 0; j2 < 4; ++j2) acc[i][j2] = (f32x4){0.f, 0.f, 0.f, 0.f};

  bf16x8 ra[4][2], rb0[2][2], rb1[2][2];

#define FENCE asm volatile("" ::: "memory")
#define STG(ab, g, ld_, bufb, h, kc) do {                                        \
    gll16((g) + (size_t)(h) * 128 * (ld_) + (kc),                                \
          smw + (bufb) + (ab) * 32768 + (h) * 16384);                            \
    gll16((g) + ((size_t)(h) * 128 + 64) * (ld_) + (kc),                         \
          smw + (bufb) + (ab) * 32768 + (h) * 16384 + 8192);                     \
  } while (0)

  const int NT = K >> 6;

  // ---- prologue: tile0 {A0,B0,A1,B1}; tile1 {A0,B0,A1} ----
  STG(0, gA, lda, 0, 0, 0);
  STG(1, gB, ldb, 0, 0, 0);
  STG(0, gA, lda, 0, 1, 0);
  STG(1, gB, ldb, 0, 1, 0);
  if (NT > 1) {
    STG(0, gA, lda, 65536, 0, 64);
    STG(1, gB, ldb, 65536, 0, 64);
    STG(0, gA, lda, 65536, 1, 64);
    asm volatile("s_waitcnt vmcnt(6)" ::: "memory");   // tile0 fully landed
  } else {
    asm volatile("s_waitcnt vmcnt(0)" ::: "memory");
  }
  FENCE; __builtin_amdgcn_s_barrier(); FENCE;

  for (int kt = 0; kt < NT; ++kt) {
    const int bufb  = (kt & 1) << 16;
    const int nbufb = bufb ^ 65536;
    const char* sA = sm + bufb;
    const char* sB = sm + bufb + 32768;

    // ---- region 1: reads A-lo + B0 + B1; stage B1(t+1)->nbuf; q1, q2 ----
#pragma unroll
    for (int mi = 0; mi < 4; ++mi) {
      ra[mi][0] = *(const bf16x8*)(sA + roA[mi] + ck0);
      ra[mi][1] = *(const bf16x8*)(sA + roA[mi] + ck1);
    }
#pragma unroll
    for (int ni = 0; ni < 2; ++ni) {
      rb0[ni][0] = *(const bf16x8*)(sB + roB[ni] + ck0);
      rb0[ni][1] = *(const bf16x8*)(sB + roB[ni] + ck1);
      rb1[ni][0] = *(const bf16x8*)(sB + roB[2 + ni] + ck0);
      rb1[ni][1] = *(const bf16x8*)(sB + roB[2 + ni] + ck1);
    }
    if (kt + 1 < NT) STG(1, gB, ldb, nbufb, 1, (kt + 1) * 64);
    __builtin_amdgcn_s_setprio(1);
#pragma unroll
    for (int mi = 0; mi < 4; ++mi)
#pragma unroll
      for (int ni = 0; ni < 2; ++ni) {
        acc[mi][ni] = __builtin_amdgcn_mfma_f32_16x16x32_bf16(ra[mi][0], rb0[ni][0], acc[mi][ni], 0, 0, 0);
        acc[mi][ni] = __builtin_amdgcn_mfma_f32_16x16x32_bf16(ra[mi][1], rb0[ni][1], acc[mi][ni], 0, 0, 0);
      }
#pragma unroll
    for (int mi = 0; mi < 4; ++mi)
#pragma unroll
      for (int ni = 0; ni < 2; ++ni) {
        acc[mi][2 + ni] = __builtin_amdgcn_mfma_f32_16x16x32_bf16(ra[mi][0], rb1[ni][0], acc[mi][2 + ni], 0, 0, 0);
        acc[mi][2 + ni] = __builtin_amdgcn_mfma_f32_16x16x32_bf16(ra[mi][1], rb1[ni][1], acc[mi][2 + ni], 0, 0, 0);
      }
    __builtin_amdgcn_s_setprio(0);
    // every wave consumed rb0/rb1 before issuing q2 -> B reads drained
    FENCE; __builtin_amdgcn_s_barrier(); FENCE;

    // ---- region 2: reads A-hi; stage B0(t+2)->cur; q3 ----
#pragma unroll
    for (int mi = 0; mi < 4; ++mi) {
      ra[mi][0] = *(const bf16x8*)(sA + roA[4 + mi] + ck0);
      ra[mi][1] = *(const bf16x8*)(sA + roA[4 + mi] + ck1);
    }
    if (kt + 2 < NT) STG(1, gB, ldb, bufb, 0, (kt + 2) * 64);
    __builtin_amdgcn_s_setprio(1);
#pragma unroll
    for (int mi = 0; mi < 4; ++mi)
#pragma unroll
      for (int ni = 0; ni < 2; ++ni) {
        acc[4 + mi][2 + ni] = __builtin_amdgcn_mfma_f32_16x16x32_bf16(ra[mi][0], rb1[ni][0], acc[4 + mi][2 + ni], 0, 0, 0);
        acc[4 + mi][2 + ni] = __builtin_amdgcn_mfma_f32_16x16x32_bf16(ra[mi][1], rb1[ni][1], acc[4 + mi][2 + ni], 0, 0, 0);
      }
    __builtin_amdgcn_s_setprio(0);
    // every wave consumed ra (A-hi) before issuing q3; A-lo drained in R1
    FENCE; __builtin_amdgcn_s_barrier(); FENCE;

    // ---- stage A0+A1(t+2)->cur; q4 (pure-register); boundary ----
    if (kt + 2 < NT) {
      STG(0, gA, lda, bufb, 0, (kt + 2) * 64);
      STG(0, gA, lda, bufb, 1, (kt + 2) * 64);
    }
    __builtin_amdgcn_s_setprio(1);
#pragma unroll
    for (int mi = 0; mi < 4; ++mi)
#pragma unroll
      for (int ni = 0; ni < 2; ++ni) {
        acc[4 + mi][ni] = __builtin_amdgcn_mfma_f32_16x16x32_bf16(ra[mi][0], rb0[ni][0], acc[4 + mi][ni], 0, 0, 0);
        acc[4 + mi][ni] = __builtin_amdgcn_mfma_f32_16x16x32_bf16(ra[mi][1], rb0[ni][1], acc[4 + mi][ni], 0, 0, 0);
      }
    __builtin_amdgcn_s_setprio(0);
    if (kt + 2 < NT) asm volatile("s_waitcnt vmcnt(6)" ::: "memory");  // tile t+1 landed, t+2's 6 in flight
    else             asm volatile("s_waitcnt vmcnt(0)" ::: "memory");  // tail drain
    FENCE; __builtin_amdgcn_s_barrier(); FENCE;
  }
#undef STG
#undef FENCE

  // ---------------- epilogue ----------------
  const int colBase = tileN + wn * 64;
  const int rowBase = tileM + wm * 128;

  if (MODE == 1) {
    if (colBase < 1024) {
      // Q: softmax over the 64-col head chunk (no max-sub: |logit| < ~4), *SCALE
#pragma unroll
      for (int mi = 0; mi < 8; ++mi) {
#pragma unroll
        for (int r = 0; r < 4; ++r) {
          float e0 = __expf(acc[mi][0][r]), e1 = __expf(acc[mi][1][r]);
          float e2 = __expf(acc[mi][2][r]), e3 = __expf(acc[mi][3][r]);
          float s = (e0 + e1) + (e2 + e3);
          s += __shfl_xor(s, 1); s += __shfl_xor(s, 2);
          s += __shfl_xor(s, 4); s += __shfl_xor(s, 8);
          float inv = 0.125f / s;   // SCALE = DH^-0.5
          int row = rowBase + mi * 16 + q * 4 + r;
          uint2 pv = { pk2(e0 * inv, e1 * inv), pk2(e2 * inv, e3 * inv) };
          *(uint2*)(Lout + (size_t)row * ldc + colBase + cl * 4) = pv;
        }
      }
    } else if (colBase < 2048) {
      // K: exp, packed store, accumulate column sums Z (logical col = cl*4+ni)
      float zp0 = 0.f, zp1 = 0.f, zp2 = 0.f, zp3 = 0.f;
      const int b = tileM / rows_per_batch;
#pragma unroll
      for (int mi = 0; mi < 8; ++mi) {
#pragma unroll
        for (int r = 0; r < 4; ++r) {
          float e0 = __expf(acc[mi][0][r]), e1 = __expf(acc[mi][1][r]);
          float e2 = __expf(acc[mi][2][r]), e3 = __expf(acc[mi][3][r]);
          zp0 += e0; zp1 += e1; zp2 += e2; zp3 += e3;
          int row = rowBase + mi * 16 + q * 4 + r;
          uint2 pv = { pk2(e0, e1), pk2(e2, e3) };
          *(uint2*)(Lout + (size_t)row * ldc + colBase + cl * 4) = pv;
        }
      }
      float zp[4] = { zp0, zp1, zp2, zp3 };
#pragma unroll
      for (int ni = 0; ni < 4; ++ni) {
        float z = zp[ni];
        z += __shfl_xor(z, 16);
        z += __shfl_xor(z, 32);
        if (q == 0) atomicAdd(&Zp[b * 1024 + (colBase - 1024) + cl * 4 + ni], z);
      }
    } else {
      // V: packed bf16 store
#pragma unroll
      for (int mi = 0; mi < 8; ++mi) {
#pragma unroll
        for (int r = 0; r < 4; ++r) {
          int row = rowBase + mi * 16 + q * 4 + r;
          uint2 pv = { pk2(acc[mi][0][r], acc[mi][1][r]),
                       pk2(acc[mi][2][r], acc[mi][3][r]) };
          *(uint2*)(Lout + (size_t)row * ldc + colBase + cl * 4) = pv;
        }
      }
    }
  } else {
    // MODE 2: f32 + bias, float4 coalesced stores (logical col = cl*4+ni)
    const float4 bb = *(const float4*)(bias + colBase + cl * 4);
#pragma unroll
    for (int mi = 0; mi < 8; ++mi) {
#pragma unroll
      for (int r = 0; r < 4; ++r) {
        int row = rowBase + mi * 16 + q * 4 + r;
        float4 v = { acc[mi][0][r] + bb.x, acc[mi][1][r] + bb.y,
                     acc[mi][2][r] + bb.z, acc[mi][3][r] + bb.w };
        *(float4*)(Fout + (size_t)row * ldc + colBase + cl * 4) = v;
      }
    }
  }
}

// ---------------------------------------------------------------------------
// ctx partials via MFMA: part[bh][wslot][d][pe] = sum_{s in slot} expK[s,d]*V[s,e]
__global__ __launch_bounds__(256) void ctx_mfma(const u16* __restrict__ L,
                                                float* __restrict__ part) {
  __shared__ __align__(16) u16 kvt[4][2][64 * 40];   // [wave][K/V][d][s], stride 40
  const int bh = blockIdx.y, b = bh >> 4, h = bh & 15;
  const int lane = threadIdx.x & 63, w = threadIdx.x >> 6;
  u16* kt = &kvt[w][0][0];
  u16* vt = &kvt[w][1][0];
  const int sl = lane & 31, half = lane >> 5;
  const int cl = lane & 15, q = lane >> 4;

  f32x4 acc[4][4];
#pragma unroll
  for (int i = 0; i < 4; ++i)
#pragma unroll
    for (int j = 0; j < 4; ++j) acc[i][j] = (f32x4){0.f, 0.f, 0.f, 0.f};

  const int sbase0 = blockIdx.x * 1024 + w * 256;
  for (int c = 0; c < 8; ++c) {
    const size_t rowb = ((size_t)b * 8192 + sbase0 + c * 32 + sl) * 3072;
#pragma unroll
    for (int dblk = 0; dblk < 4; ++dblk) {
      int d0 = dblk * 16 + half * 8;
      u16x8 kv = *(const u16x8*)(L + rowb + 1024 + h * 64 + d0);
      u16x8 vv = *(const u16x8*)(L + rowb + 2048 + h * 64 + d0);
#pragma unroll
      for (int j = 0; j < 8; ++j) {
        kt[(d0 + j) * 40 + sl] = kv[j];
        vt[(d0 + j) * 40 + sl] = vv[j];
      }
    }
    bf16x8 af[4], bfr[4];
#pragma unroll
    for (int mi = 0; mi < 4; ++mi) af[mi]  = *(const bf16x8*)&kt[(mi * 16 + cl) * 40 + q * 8];
#pragma unroll
    for (int ni = 0; ni < 4; ++ni) bfr[ni] = *(const bf16x8*)&vt[(ni * 16 + cl) * 40 + q * 8];
#pragma unroll
    for (int mi = 0; mi < 4; ++mi)
#pragma unroll
      for (int ni = 0; ni < 4; ++ni)
        acc[mi][ni] = __builtin_amdgcn_mfma_f32_16x16x32_bf16(af[mi], bfr[ni], acc[mi][ni], 0, 0, 0);
  }

  const int wslot = blockIdx.x * 4 + w;
  float* pb = part + ((size_t)bh * 32 + wslot) * 4096;
#pragma unroll
  for (int mi = 0; mi < 4; ++mi)
#pragma unroll
    for (int r = 0; r < 4; ++r) {
      float4 v = { acc[mi][0][r], acc[mi][1][r], acc[mi][2][r], acc[mi][3][r] };
      *(float4*)(pb + (mi * 16 + q * 4 + r) * 64 + cl * 4) = v;
    }
}

// cn[bh][d][pe] = (sum_w part[bh][w][d][pe]) / Z[b*1024 + h*64 + d]
__global__ __launch_bounds__(256) void norm_ctx(const float* __restrict__ part,
                                                const float* __restrict__ Z,
                                                float* __restrict__ cn) {
  int i = blockIdx.x * 256 + threadIdx.x;   // 262144
  int bh = i >> 12, rest = i & 4095, d = rest >> 6;
  float s = 0.f;
#pragma unroll
  for (int w = 0; w < 32; ++w) s += part[((size_t)bh * 32 + w) * 4096 + rest];
  cn[i] = s / Z[(bh >> 4) * 1024 + (bh & 15) * 64 + d];
}

// Weff_t[b][p][h*64+d] = sum_pe cn[bh][d][pe] * Wlin[(h*64+e(pe))*1024 + lam(p)]
__global__ __launch_bounds__(256) void weff_k(const float* __restrict__ cn,
                                              const float* __restrict__ Wlin,
                                              u16* __restrict__ Wt) {
  int bh = blockIdx.y; int b = bh >> 4, h = bh & 15;
  int p = blockIdx.x * 256 + threadIdx.x;
  int up = p & 63;
  int j = (p & ~63) | ((up & 15) << 2) | (up >> 4);   // logical out col
  const float* c = cn + (size_t)bh * 4096;
  float out[64];
#pragma unroll
  for (int d = 0; d < 64; ++d) out[d] = 0.f;
  for (int pe = 0; pe < 64; ++pe) {
    int e = ((pe & 3) << 4) | (pe >> 2);              // logical e at stored pos pe
    float wv = Wlin[(size_t)(h * 64 + e) * 1024 + j];
#pragma unroll
    for (int d = 0; d < 64; ++d) out[d] += c[d * 64 + pe] * wv;
  }
  u16* dst = Wt + ((size_t)b * 1024 + p) * 1024 + h * 64;
#pragma unroll
  for (int d0 = 0; d0 < 64; d0 += 2)
    *(u32*)(dst + d0) = pk2(out[d0], out[d0 + 1]);
}

// ---------------------------------------------------------------------------
extern "C" void kernel_launch(void* const* d_in, const int* in_sizes, int n_in,
                              void* d_out, int out_size, void* d_ws, size_t ws_size,
                              hipStream_t stream) {
  const float* x    = (const float*)d_in[0];
  const float* Wq   = (const float*)d_in[1];
  const float* Wkv  = (const float*)d_in[2];
  const float* Wlin = (const float*)d_in[3];
  const float* blin = (const float*)d_in[4];
  float* out = (float*)d_out;
  char* ws = (char*)d_ws;

  // phase-1 workspace
  u16*   xb   = (u16*)(ws);                    // 64 MB : x bf16 (32768 x 1024)
  u16*   w3t  = (u16*)(ws + 67108864);         // 6 MB  : W3^T bf16 (3072 x 1024), permuted
  u16*   L    = (u16*)(ws + 73400320);         // 192 MB: [Qs | expK | V] bf16 (32768 x 3072)
  float* Zp   = (float*)(ws + 274726912);      // 16 KB : K-softmax denominators (4 x 1024)
  // phase-2 workspace (reuses xb region; xb is dead after GEMM1)
  float* part = (float*)(ws);                  // 32 MB : ctx partials (64 x 32 x 64 x 64)
  float* cn   = (float*)(ws + 33554432);       // 1 MB  : ctx normalized (permuted e)
  u16*   weff = (u16*)(ws + 34603008);         // 8 MB  : Weff^T bf16 (4 x 1024 x 1024), permuted rows

  hipMemsetAsync(Zp, 0, 16384, stream);

  cvt_x<<<32768, 256, 0, stream>>>(x, xb, 33554432);
  build_w3t<<<dim3(96, 32), 256, 0, stream>>>(Wq, Wkv, w3t);

  gemm_bt_k<1><<<dim3(12, 128), 512, 0, stream>>>(
      xb, 1024, w3t, 1024, 1024, L, 3072, nullptr, Zp, nullptr, (size_t)0, 8192);

  ctx_mfma<<<dim3(8, 64), 256, 0, stream>>>(L, part);
  norm_ctx<<<1024, 256, 0, stream>>>(part, Zp, cn);
  weff_k<<<dim3(4, 64), 256, 0, stream>>>(cn, Wlin, weff);

  gemm_bt_k<2><<<dim3(4, 128), 512, 0, stream>>>(
      L, 3072, weff, 1024, 1024, nullptr, 1024, out, nullptr, blin, (size_t)1048576, 8192);
}

// Round 4
// 590.266 us; speedup vs baseline: 1.0206x; 1.0206x over previous
//
#include <hip/hip_runtime.h>
#include <cstdint>
#include <cstddef>

typedef unsigned short u16;
typedef unsigned int u32;
typedef __attribute__((ext_vector_type(8))) __bf16 bf16x8;
typedef __attribute__((ext_vector_type(4))) float f32x4;
typedef __attribute__((ext_vector_type(2))) unsigned int u32x2;
typedef __attribute__((ext_vector_type(8))) unsigned short u16x8;
typedef __attribute__((ext_vector_type(4))) unsigned short u16x4;

__device__ __forceinline__ u16 f2bf(float f) {
  union { float f; unsigned u; } v; v.f = f;
  unsigned r = v.u + 0x7fffu + ((v.u >> 16) & 1u);   // RNE
  return (u16)(r >> 16);
}
__device__ __forceinline__ float bf2f(u16 x) {
  union { float f; unsigned u; } v; v.u = ((unsigned)x) << 16;
  return v.f;
}
// pack two f32 -> two bf16 (RNE)
__device__ __forceinline__ u32 pk2(float a, float b) {
  union { float f; unsigned u; } x, y; x.f = a; y.f = b;
  unsigned ra = x.u + 0x7fffu + ((x.u >> 16) & 1u);
  unsigned rb = y.u + 0x7fffu + ((y.u >> 16) & 1u);
  return (ra >> 16) | (rb & 0xffff0000u);
}

__device__ __forceinline__ void gll16(const void* g, void* l) {
  __builtin_amdgcn_global_load_lds(
      (const __attribute__((address_space(1))) void*)g,
      (__attribute__((address_space(3))) void*)l, 16, 0, 0);
}

// ---------------------------------------------------------------------------
// x (f32) -> bf16.  x is single-use -> nontemporal load (don't pollute L2/L3).
__global__ __launch_bounds__(256) void cvt_x(const float* __restrict__ x,
                                             u16* __restrict__ xb, int n) {
  int i = (blockIdx.x * 256 + threadIdx.x) * 4;
  if (i < n) {
    f32x4 v = __builtin_nontemporal_load((const f32x4*)(x + i));
    u16x4 o = { f2bf(v[0]), f2bf(v[1]), f2bf(v[2]), f2bf(v[3]) };
    *(u16x4*)(xb + i) = o;   // xb is heavily reused by GEMM1 -> normal store
  }
}

// ---------------------------------------------------------------------------
// W3^T (3072 x 1024) bf16, with per-64-chunk column permutation baked in:
// physical row n holds LOGICAL column (n&~63) | lam(n&63), lam(u)=(u&15)*4+(u>>4).
__global__ __launch_bounds__(256) void build_w3t(const float* __restrict__ Wq,
                                                 const float* __restrict__ Wkv,
                                                 u16* __restrict__ W3t) {
  __shared__ float tile[32][33];
  int bx = blockIdx.x, by = blockIdx.y;          // bx: n-tile (96), by: k-tile (32)
  int tx = threadIdx.x & 31, tyb = threadIdx.x >> 5;
  int n = bx * 32 + tx;                          // physical row
  int u = n & 63;
  int nl = (n & ~63) | ((u & 15) << 2) | (u >> 4);  // logical column
  const float* src; int scol, sld;
  if (nl < 1024)      { src = Wq;  scol = nl;                                  sld = 1024; }
  else if (nl < 2048) { int m = nl - 1024; src = Wkv; scol = (m >> 6) * 128 + (m & 63);      sld = 2048; }
  else                { int m = nl - 2048; src = Wkv; scol = (m >> 6) * 128 + 64 + (m & 63); sld = 2048; }
#pragma unroll
  for (int i = 0; i < 4; ++i) {
    int k = by * 32 + tyb + i * 8;
    tile[tyb + i * 8][tx] = src[(size_t)k * sld + scol];
  }
  __syncthreads();
#pragma unroll
  for (int i = 0; i < 4; ++i) {
    int n2 = bx * 32 + tyb + i * 8;
    int k2 = by * 32 + tx;
    W3t[(size_t)n2 * 1024 + k2] = f2bf(tile[tx][tyb + i * 8]);
  }
}

// ---------------------------------------------------------------------------
// 256x256 bf16 GEMM, merged-region schedule: 3 barriers / K-tile.
// 512 thr = 8 waves (2M x 4N), BK=64, LDS 128 KiB dbuf, counted vmcnt(6),
// XOR-swizzled LDS reads with pre-swizzled global staging (linear LDS dest).
//
// Memory-hierarchy discipline (round 4):
//  - epilogue stores are NONTEMPORAL: the 192 MB (M1) / 128 MB (M2) write
//    stream otherwise thrashes L3 and demotes A-panel re-reads to HBM
//    (measured FETCH_SIZE 405 MB vs ~70 MB ideal).
//  - XCD chunk walk is N-FASTEST: working set per XCD = 1 A panel (512 KB)
//    + CN B panels (<=3 MB) -> both L2-resident; A read once per XCD.
//
// MODE 1: epilogue QKV (Q: row-softmax*SCALE; K: exp + Z col-sums; V: raw) -> bf16 L
// MODE 2: f32 out + bias, Bt batched by tileM/rows_per_batch.
template <int MODE>
__global__ __launch_bounds__(512, 2)
void gemm_bt_k(const u16* __restrict__ A, int lda,
               const u16* __restrict__ Bt0, int ldb, int K,
               u16* __restrict__ Lout, int ldc,
               float* __restrict__ Fout,
               float* __restrict__ Zp, const float* __restrict__ bias,
               size_t bstride, int rows_per_batch) {
  __shared__ __align__(16) char sm[131072];   // [buf][A|B]: buf*65536 + ab*32768
  const int tid  = threadIdx.x;
  const int lane = tid & 63, w = tid >> 6;
  const int wm = w >> 2, wn = w & 3;

  // XCD-aware 2D chunk decode (requires nby%4==0, nbx%2==0, bijective),
  // N-fastest walk within a chunk.
  const int nbx = gridDim.x;                 // N tiles
  const int nby = gridDim.y;                 // M tiles
  const int o = blockIdx.y * nbx + blockIdx.x;
  const int x = o & 7, j = o >> 3;
  const int CM = nby >> 2, CN = nbx >> 1;    // chunk = CM x CN tiles
  const int jn = j % CN, jm = j / CN;        // N-fastest within chunk
  const int tileM = ((x >> 1) * CM + jm) * 256;
  const int tileN = ((x & 1) * CN + jn) * 256;

  const u16* Bt = Bt0;
  if (MODE == 2) Bt += (size_t)(tileM / rows_per_batch) * bstride;

  // ---- staging addressing (global source pre-swizzled, LDS dest linear) ----
  const int r0 = tid >> 3;                   // row within 64-row round
  const int pp = (tid & 7) ^ (r0 & 7);       // swizzled 16B chunk within 128B row
  const u16* gA = A  + (size_t)(tileM + r0) * lda + pp * 8;
  const u16* gB = Bt + (size_t)(tileN + r0) * ldb + pp * 8;
  char* smw = sm + w * 1024;                 // wave-uniform LDS base (round 0)

  // ---- ds_read addressing (swizzled) ----
  const int cl = lane & 15, q = lane >> 4;
  int roA[8], roB[4];
#pragma unroll
  for (int mi = 0; mi < 8; ++mi) roA[mi] = (wm * 128 + mi * 16 + cl) * 128;
#pragma unroll
  for (int ni = 0; ni < 4; ++ni) roB[ni] = (wn * 64 + ni * 16 + cl) * 128;
  const int ck0 = ((0 + q) ^ (cl & 7)) * 16;
  const int ck1 = ((4 + q) ^ (cl & 7)) * 16;

  f32x4 acc[8][4];
#pragma unroll
  for (int i = 0; i < 8; ++i)
#pragma unroll
    for (int j2 = 0; j2 < 4; ++j2) acc[i][j2] = (f32x4){0.f, 0.f, 0.f, 0.f};

  bf16x8 ra[4][2], rb0[2][2], rb1[2][2];

#define FENCE asm volatile("" ::: "memory")
#define STG(ab, g, ld_, bufb, h, kc) do {                                        \
    gll16((g) + (size_t)(h) * 128 * (ld_) + (kc),                                \
          smw + (bufb) + (ab) * 32768 + (h) * 16384);                            \
    gll16((g) + ((size_t)(h) * 128 + 64) * (ld_) + (kc),                         \
          smw + (bufb) + (ab) * 32768 + (h) * 16384 + 8192);                     \
  } while (0)

  const int NT = K >> 6;

  // ---- prologue: tile0 {A0,B0,A1,B1}; tile1 {A0,B0,A1} ----
  STG(0, gA, lda, 0, 0, 0);
  STG(1, gB, ldb, 0, 0, 0);
  STG(0, gA, lda, 0, 1, 0);
  STG(1, gB, ldb, 0, 1, 0);
  if (NT > 1) {
    STG(0, gA, lda, 65536, 0, 64);
    STG(1, gB, ldb, 65536, 0, 64);
    STG(0, gA, lda, 65536, 1, 64);
    asm volatile("s_waitcnt vmcnt(6)" ::: "memory");   // tile0 fully landed
  } else {
    asm volatile("s_waitcnt vmcnt(0)" ::: "memory");
  }
  FENCE; __builtin_amdgcn_s_barrier(); FENCE;

  for (int kt = 0; kt < NT; ++kt) {
    const int bufb  = (kt & 1) << 16;
    const int nbufb = bufb ^ 65536;
    const char* sA = sm + bufb;
    const char* sB = sm + bufb + 32768;

    // ---- region 1: reads A-lo + B0 + B1; stage B1(t+1)->nbuf; q1, q2 ----
#pragma unroll
    for (int mi = 0; mi < 4; ++mi) {
      ra[mi][0] = *(const bf16x8*)(sA + roA[mi] + ck0);
      ra[mi][1] = *(const bf16x8*)(sA + roA[mi] + ck1);
    }
#pragma unroll
    for (int ni = 0; ni < 2; ++ni) {
      rb0[ni][0] = *(const bf16x8*)(sB + roB[ni] + ck0);
      rb0[ni][1] = *(const bf16x8*)(sB + roB[ni] + ck1);
      rb1[ni][0] = *(const bf16x8*)(sB + roB[2 + ni] + ck0);
      rb1[ni][1] = *(const bf16x8*)(sB + roB[2 + ni] + ck1);
    }
    if (kt + 1 < NT) STG(1, gB, ldb, nbufb, 1, (kt + 1) * 64);
    __builtin_amdgcn_s_setprio(1);
#pragma unroll
    for (int mi = 0; mi < 4; ++mi)
#pragma unroll
      for (int ni = 0; ni < 2; ++ni) {
        acc[mi][ni] = __builtin_amdgcn_mfma_f32_16x16x32_bf16(ra[mi][0], rb0[ni][0], acc[mi][ni], 0, 0, 0);
        acc[mi][ni] = __builtin_amdgcn_mfma_f32_16x16x32_bf16(ra[mi][1], rb0[ni][1], acc[mi][ni], 0, 0, 0);
      }
#pragma unroll
    for (int mi = 0; mi < 4; ++mi)
#pragma unroll
      for (int ni = 0; ni < 2; ++ni) {
        acc[mi][2 + ni] = __builtin_amdgcn_mfma_f32_16x16x32_bf16(ra[mi][0], rb1[ni][0], acc[mi][2 + ni], 0, 0, 0);
        acc[mi][2 + ni] = __builtin_amdgcn_mfma_f32_16x16x32_bf16(ra[mi][1], rb1[ni][1], acc[mi][2 + ni], 0, 0, 0);
      }
    __builtin_amdgcn_s_setprio(0);
    // every wave consumed rb0/rb1 before issuing q2 -> B reads drained
    FENCE; __builtin_amdgcn_s_barrier(); FENCE;

    // ---- region 2: reads A-hi; stage B0(t+2)->cur; q3 ----
#pragma unroll
    for (int mi = 0; mi < 4; ++mi) {
      ra[mi][0] = *(const bf16x8*)(sA + roA[4 + mi] + ck0);
      ra[mi][1] = *(const bf16x8*)(sA + roA[4 + mi] + ck1);
    }
    if (kt + 2 < NT) STG(1, gB, ldb, bufb, 0, (kt + 2) * 64);
    __builtin_amdgcn_s_setprio(1);
#pragma unroll
    for (int mi = 0; mi < 4; ++mi)
#pragma unroll
      for (int ni = 0; ni < 2; ++ni) {
        acc[4 + mi][2 + ni] = __builtin_amdgcn_mfma_f32_16x16x32_bf16(ra[mi][0], rb1[ni][0], acc[4 + mi][2 + ni], 0, 0, 0);
        acc[4 + mi][2 + ni] = __builtin_amdgcn_mfma_f32_16x16x32_bf16(ra[mi][1], rb1[ni][1], acc[4 + mi][2 + ni], 0, 0, 0);
      }
    __builtin_amdgcn_s_setprio(0);
    // every wave consumed ra (A-hi) before issuing q3; A-lo drained in R1
    FENCE; __builtin_amdgcn_s_barrier(); FENCE;

    // ---- stage A0+A1(t+2)->cur; q4 (pure-register); boundary ----
    if (kt + 2 < NT) {
      STG(0, gA, lda, bufb, 0, (kt + 2) * 64);
      STG(0, gA, lda, bufb, 1, (kt + 2) * 64);
    }
    __builtin_amdgcn_s_setprio(1);
#pragma unroll
    for (int mi = 0; mi < 4; ++mi)
#pragma unroll
      for (int ni = 0; ni < 2; ++ni) {
        acc[4 + mi][ni] = __builtin_amdgcn_mfma_f32_16x16x32_bf16(ra[mi][0], rb0[ni][0], acc[4 + mi][ni], 0, 0, 0);
        acc[4 + mi][ni] = __builtin_amdgcn_mfma_f32_16x16x32_bf16(ra[mi][1], rb0[ni][1], acc[4 + mi][ni], 0, 0, 0);
      }
    __builtin_amdgcn_s_setprio(0);
    if (kt + 2 < NT) asm volatile("s_waitcnt vmcnt(6)" ::: "memory");  // tile t+1 landed, t+2's 6 in flight
    else             asm volatile("s_waitcnt vmcnt(0)" ::: "memory");  // tail drain
    FENCE; __builtin_amdgcn_s_barrier(); FENCE;
  }
#undef STG
#undef FENCE

  // ---------------- epilogue (all global stores NONTEMPORAL) ----------------
  const int colBase = tileN + wn * 64;
  const int rowBase = tileM + wm * 128;

  if (MODE == 1) {
    if (colBase < 1024) {
      // Q: softmax over the 64-col head chunk (no max-sub: |logit| < ~4), *SCALE
#pragma unroll
      for (int mi = 0; mi < 8; ++mi) {
#pragma unroll
        for (int r = 0; r < 4; ++r) {
          float e0 = __expf(acc[mi][0][r]), e1 = __expf(acc[mi][1][r]);
          float e2 = __expf(acc[mi][2][r]), e3 = __expf(acc[mi][3][r]);
          float s = (e0 + e1) + (e2 + e3);
          s += __shfl_xor(s, 1); s += __shfl_xor(s, 2);
          s += __shfl_xor(s, 4); s += __shfl_xor(s, 8);
          float inv = 0.125f / s;   // SCALE = DH^-0.5
          int row = rowBase + mi * 16 + q * 4 + r;
          u32x2 pv = { pk2(e0 * inv, e1 * inv), pk2(e2 * inv, e3 * inv) };
          __builtin_nontemporal_store(pv, (u32x2*)(Lout + (size_t)row * ldc + colBase + cl * 4));
        }
      }
    } else if (colBase < 2048) {
      // K: exp, packed store, accumulate column sums Z (logical col = cl*4+ni)
      float zp0 = 0.f, zp1 = 0.f, zp2 = 0.f, zp3 = 0.f;
      const int b = tileM / rows_per_batch;
#pragma unroll
      for (int mi = 0; mi < 8; ++mi) {
#pragma unroll
        for (int r = 0; r < 4; ++r) {
          float e0 = __expf(acc[mi][0][r]), e1 = __expf(acc[mi][1][r]);
          float e2 = __expf(acc[mi][2][r]), e3 = __expf(acc[mi][3][r]);
          zp0 += e0; zp1 += e1; zp2 += e2; zp3 += e3;
          int row = rowBase + mi * 16 + q * 4 + r;
          u32x2 pv = { pk2(e0, e1), pk2(e2, e3) };
          __builtin_nontemporal_store(pv, (u32x2*)(Lout + (size_t)row * ldc + colBase + cl * 4));
        }
      }
      float zp[4] = { zp0, zp1, zp2, zp3 };
#pragma unroll
      for (int ni = 0; ni < 4; ++ni) {
        float z = zp[ni];
        z += __shfl_xor(z, 16);
        z += __shfl_xor(z, 32);
        if (q == 0) atomicAdd(&Zp[b * 1024 + (colBase - 1024) + cl * 4 + ni], z);
      }
    } else {
      // V: packed bf16 store
#pragma unroll
      for (int mi = 0; mi < 8; ++mi) {
#pragma unroll
        for (int r = 0; r < 4; ++r) {
          int row = rowBase + mi * 16 + q * 4 + r;
          u32x2 pv = { pk2(acc[mi][0][r], acc[mi][1][r]),
                       pk2(acc[mi][2][r], acc[mi][3][r]) };
          __builtin_nontemporal_store(pv, (u32x2*)(Lout + (size_t)row * ldc + colBase + cl * 4));
        }
      }
    }
  } else {
    // MODE 2: f32 + bias, nontemporal float4 stores (logical col = cl*4+ni)
    const float4 bb = *(const float4*)(bias + colBase + cl * 4);
#pragma unroll
    for (int mi = 0; mi < 8; ++mi) {
#pragma unroll
      for (int r = 0; r < 4; ++r) {
        int row = rowBase + mi * 16 + q * 4 + r;
        f32x4 v = { acc[mi][0][r] + bb.x, acc[mi][1][r] + bb.y,
                    acc[mi][2][r] + bb.z, acc[mi][3][r] + bb.w };
        __builtin_nontemporal_store(v, (f32x4*)(Fout + (size_t)row * ldc + colBase + cl * 4));
      }
    }
  }
}

// ---------------------------------------------------------------------------
// ctx partials via MFMA: part[bh][wslot][d][pe] = sum_{s in slot} expK[s,d]*V[s,e]
// L reads are single-use -> nontemporal loads. part is read immediately by
// norm_ctx -> normal (L3-resident) stores.
__global__ __launch_bounds__(256) void ctx_mfma(const u16* __restrict__ L,
                                                float* __restrict__ part) {
  __shared__ __align__(16) u16 kvt[4][2][64 * 40];   // [wave][K/V][d][s], stride 40
  const int bh = blockIdx.y, b = bh >> 4, h = bh & 15;
  const int lane = threadIdx.x & 63, w = threadIdx.x >> 6;
  u16* kt = &kvt[w][0][0];
  u16* vt = &kvt[w][1][0];
  const int sl = lane & 31, half = lane >> 5;
  const int cl = lane & 15, q = lane >> 4;

  f32x4 acc[4][4];
#pragma unroll
  for (int i = 0; i < 4; ++i)
#pragma unroll
    for (int j = 0; j < 4; ++j) acc[i][j] = (f32x4){0.f, 0.f, 0.f, 0.f};

  const int sbase0 = blockIdx.x * 1024 + w * 256;
  for (int c = 0; c < 8; ++c) {
    const size_t rowb = ((size_t)b * 8192 + sbase0 + c * 32 + sl) * 3072;
#pragma unroll
    for (int dblk = 0; dblk < 4; ++dblk) {
      int d0 = dblk * 16 + half * 8;
      u16x8 kv = __builtin_nontemporal_load((const u16x8*)(L + rowb + 1024 + h * 64 + d0));
      u16x8 vv = __builtin_nontemporal_load((const u16x8*)(L + rowb + 2048 + h * 64 + d0));
#pragma unroll
      for (int j = 0; j < 8; ++j) {
        kt[(d0 + j) * 40 + sl] = kv[j];
        vt[(d0 + j) * 40 + sl] = vv[j];
      }
    }
    bf16x8 af[4], bfr[4];
#pragma unroll
    for (int mi = 0; mi < 4; ++mi) af[mi]  = *(const bf16x8*)&kt[(mi * 16 + cl) * 40 + q * 8];
#pragma unroll
    for (int ni = 0; ni < 4; ++ni) bfr[ni] = *(const bf16x8*)&vt[(ni * 16 + cl) * 40 + q * 8];
#pragma unroll
    for (int mi = 0; mi < 4; ++mi)
#pragma unroll
      for (int ni = 0; ni < 4; ++ni)
        acc[mi][ni] = __builtin_amdgcn_mfma_f32_16x16x32_bf16(af[mi], bfr[ni], acc[mi][ni], 0, 0, 0);
  }

  const int wslot = blockIdx.x * 4 + w;
  float* pb = part + ((size_t)bh * 32 + wslot) * 4096;
#pragma unroll
  for (int mi = 0; mi < 4; ++mi)
#pragma unroll
    for (int r = 0; r < 4; ++r) {
      float4 v = { acc[mi][0][r], acc[mi][1][r], acc[mi][2][r], acc[mi][3][r] };
      *(float4*)(pb + (mi * 16 + q * 4 + r) * 64 + cl * 4) = v;
    }
}

// cn[bh][d][pe] = (sum_w part[bh][w][d][pe]) / Z[b*1024 + h*64 + d]
__global__ __launch_bounds__(256) void norm_ctx(const float* __restrict__ part,
                                                const float* __restrict__ Z,
                                                float* __restrict__ cn) {
  int i = blockIdx.x * 256 + threadIdx.x;   // 262144
  int bh = i >> 12, rest = i & 4095, d = rest >> 6;
  float s = 0.f;
#pragma unroll
  for (int w = 0; w < 32; ++w) s += part[((size_t)bh * 32 + w) * 4096 + rest];
  cn[i] = s / Z[(bh >> 4) * 1024 + (bh & 15) * 64 + d];
}

// Weff_t[b][p][h*64+d] = sum_pe cn[bh][d][pe] * Wlin[(h*64+e(pe))*1024 + lam(p)]
__global__ __launch_bounds__(256) void weff_k(const float* __restrict__ cn,
                                              const float* __restrict__ Wlin,
                                              u16* __restrict__ Wt) {
  int bh = blockIdx.y; int b = bh >> 4, h = bh & 15;
  int p = blockIdx.x * 256 + threadIdx.x;
  int up = p & 63;
  int j = (p & ~63) | ((up & 15) << 2) | (up >> 4);   // logical out col
  const float* c = cn + (size_t)bh * 4096;
  float out[64];
#pragma unroll
  for (int d = 0; d < 64; ++d) out[d] = 0.f;
  for (int pe = 0; pe < 64; ++pe) {
    int e = ((pe & 3) << 4) | (pe >> 2);              // logical e at stored pos pe
    float wv = Wlin[(size_t)(h * 64 + e) * 1024 + j];
#pragma unroll
    for (int d = 0; d < 64; ++d) out[d] += c[d * 64 + pe] * wv;
  }
  u16* dst = Wt + ((size_t)b * 1024 + p) * 1024 + h * 64;
#pragma unroll
  for (int d0 = 0; d0 < 64; d0 += 2)
    *(u32*)(dst + d0) = pk2(out[d0], out[d0 + 1]);
}

// ---------------------------------------------------------------------------
extern "C" void kernel_launch(void* const* d_in, const int* in_sizes, int n_in,
                              void* d_out, int out_size, void* d_ws, size_t ws_size,
                              hipStream_t stream) {
  const float* x    = (const float*)d_in[0];
  const float* Wq   = (const float*)d_in[1];
  const float* Wkv  = (const float*)d_in[2];
  const float* Wlin = (const float*)d_in[3];
  const float* blin = (const float*)d_in[4];
  float* out = (float*)d_out;
  char* ws = (char*)d_ws;

  // phase-1 workspace
  u16*   xb   = (u16*)(ws);                    // 64 MB : x bf16 (32768 x 1024)
  u16*   w3t  = (u16*)(ws + 67108864);         // 6 MB  : W3^T bf16 (3072 x 1024), permuted
  u16*   L    = (u16*)(ws + 73400320);         // 192 MB: [Qs | expK | V] bf16 (32768 x 3072)
  float* Zp   = (float*)(ws + 274726912);      // 16 KB : K-softmax denominators (4 x 1024)
  // phase-2 workspace (reuses xb region; xb is dead after GEMM1)
  float* part = (float*)(ws);                  // 32 MB : ctx partials (64 x 32 x 64 x 64)
  float* cn   = (float*)(ws + 33554432);       // 1 MB  : ctx normalized (permuted e)
  u16*   weff = (u16*)(ws + 34603008);         // 8 MB  : Weff^T bf16 (4 x 1024 x 1024), permuted rows

  hipMemsetAsync(Zp, 0, 16384, stream);

  cvt_x<<<32768, 256, 0, stream>>>(x, xb, 33554432);
  build_w3t<<<dim3(96, 32), 256, 0, stream>>>(Wq, Wkv, w3t);

  gemm_bt_k<1><<<dim3(12, 128), 512, 0, stream>>>(
      xb, 1024, w3t, 1024, 1024, L, 3072, nullptr, Zp, nullptr, (size_t)0, 8192);

  ctx_mfma<<<dim3(8, 64), 256, 0, stream>>>(L, part);
  norm_ctx<<<1024, 256, 0, stream>>>(part, Zp, cn);
  weff_k<<<dim3(4, 64), 256, 0, stream>>>(cn, Wlin, weff);

  gemm_bt_k<2><<<dim3(4, 128), 512, 0, stream>>>(
      L, 3072, weff, 1024, 1024, nullptr, 1024, out, nullptr, blin, (size_t)1048576, 8192);
}

// Round 5
// 586.510 us; speedup vs baseline: 1.0271x; 1.0064x over previous
//
#include <hip/hip_runtime.h>
#include <cstdint>
#include <cstddef>

typedef unsigned short u16;
typedef unsigned int u32;
typedef __attribute__((ext_vector_type(8))) __bf16 bf16x8;
typedef __attribute__((ext_vector_type(4))) float f32x4;
typedef __attribute__((ext_vector_type(2))) unsigned int u32x2;
typedef __attribute__((ext_vector_type(8))) unsigned short u16x8;
typedef __attribute__((ext_vector_type(4))) unsigned short u16x4;

__device__ __forceinline__ u16 f2bf(float f) {
  union { float f; unsigned u; } v; v.f = f;
  unsigned r = v.u + 0x7fffu + ((v.u >> 16) & 1u);   // RNE
  return (u16)(r >> 16);
}
__device__ __forceinline__ float bf2f(u16 x) {
  union { float f; unsigned u; } v; v.u = ((unsigned)x) << 16;
  return v.f;
}
// pack two f32 -> two bf16 (RNE)
__device__ __forceinline__ u32 pk2(float a, float b) {
  union { float f; unsigned u; } x, y; x.f = a; y.f = b;
  unsigned ra = x.u + 0x7fffu + ((x.u >> 16) & 1u);
  unsigned rb = y.u + 0x7fffu + ((y.u >> 16) & 1u);
  return (ra >> 16) | (rb & 0xffff0000u);
}

__device__ __forceinline__ void gll16(const void* g, void* l) {
  __builtin_amdgcn_global_load_lds(
      (const __attribute__((address_space(1))) void*)g,
      (__attribute__((address_space(3))) void*)l, 16, 0, 0);
}

// ---------------------------------------------------------------------------
// x (f32) -> bf16.  x is single-use -> nontemporal load.
__global__ __launch_bounds__(256) void cvt_x(const float* __restrict__ x,
                                             u16* __restrict__ xb, int n) {
  int i = (blockIdx.x * 256 + threadIdx.x) * 4;
  if (i < n) {
    f32x4 v = __builtin_nontemporal_load((const f32x4*)(x + i));
    u16x4 o = { f2bf(v[0]), f2bf(v[1]), f2bf(v[2]), f2bf(v[3]) };
    *(u16x4*)(xb + i) = o;   // xb reused by GEMM1 -> normal store
  }
}

// ---------------------------------------------------------------------------
// W3^T (3072 x 1024) bf16, per-64-chunk column permutation baked in:
// physical row n holds LOGICAL column (n&~63) | lam(n&63), lam(u)=(u&15)*4+(u>>4).
__global__ __launch_bounds__(256) void build_w3t(const float* __restrict__ Wq,
                                                 const float* __restrict__ Wkv,
                                                 u16* __restrict__ W3t) {
  __shared__ float tile[32][33];
  int bx = blockIdx.x, by = blockIdx.y;          // bx: n-tile (96), by: k-tile (32)
  int tx = threadIdx.x & 31, tyb = threadIdx.x >> 5;
  int n = bx * 32 + tx;                          // physical row
  int u = n & 63;
  int nl = (n & ~63) | ((u & 15) << 2) | (u >> 4);  // logical column
  const float* src; int scol, sld;
  if (nl < 1024)      { src = Wq;  scol = nl;                                  sld = 1024; }
  else if (nl < 2048) { int m = nl - 1024; src = Wkv; scol = (m >> 6) * 128 + (m & 63);      sld = 2048; }
  else                { int m = nl - 2048; src = Wkv; scol = (m >> 6) * 128 + 64 + (m & 63); sld = 2048; }
#pragma unroll
  for (int i = 0; i < 4; ++i) {
    int k = by * 32 + tyb + i * 8;
    tile[tyb + i * 8][tx] = src[(size_t)k * sld + scol];
  }
  __syncthreads();
#pragma unroll
  for (int i = 0; i < 4; ++i) {
    int n2 = bx * 32 + tyb + i * 8;
    int k2 = by * 32 + tx;
    W3t[(size_t)n2 * 1024 + k2] = f2bf(tile[tx][tyb + i * 8]);
  }
}

// ---------------------------------------------------------------------------
// PERSISTENT 256x256 bf16 GEMM, merged-region schedule (3 barriers / K-tile),
// counted vmcnt(6), XOR-swizzled LDS reads, pre-swizzled global staging.
//
// Grid = 256 blocks, each runs CN assignments as ONE uniform virtual-K-loop
// (v = 0..CN*16): staging ledger / buffer parity / vmcnt boundaries continue
// seamlessly across assignment boundaries -> next assignment's first tiles
// prefetched during the previous one's last tiles; epilogue (register+store
// only) overlaps the in-flight stages. Assignment mapping reproduces the
// previous grid's per-round concurrency (same A-panel L2 sharing):
//   o = a*256 + p; xcd = p&7; j = a*32 + p>>3; jn = j%CN, jm = j/CN.
//
// K is fixed = 1024 (NT=16) in this pipeline: v>>4 = assignment, v&15 = kt.
//
// MODE 1: epilogue QKV (Q: row-softmax*SCALE; K: exp + Z col-sums; V: raw) -> bf16 L
// MODE 2: f32 out + bias, Bt batched by tileM/rows_per_batch.
template <int MODE, int CN>
__global__ __launch_bounds__(512, 2)
void gemm_bt_k(const u16* __restrict__ A, int lda,
               const u16* __restrict__ Bt0, int ldb, int K,
               u16* __restrict__ Lout, int ldc,
               float* __restrict__ Fout,
               float* __restrict__ Zp, const float* __restrict__ bias,
               size_t bstride, int rows_per_batch) {
  __shared__ __align__(16) char sm[131072];   // [buf][A|B]: buf*65536 + ab*32768
  const int tid  = threadIdx.x;
  const int lane = tid & 63, w = tid >> 6;
  const int wm = w >> 2, wn = w & 3;

  const int p = blockIdx.x, xc = p & 7, sslot = p >> 3;

  // assignment a -> (tileM, tileN); uniform scalar math (CN is constexpr)
  auto tileOf = [&](int a, int& tM, int& tN) {
    int j = a * 32 + sslot;
    int jm = j / CN, jn = j % CN;
    tM = ((xc >> 1) * 32 + jm) * 256;
    tN = ((xc & 1) * CN + jn) * 256;
  };

  // ---- staging addressing (global source pre-swizzled, LDS dest linear) ----
  const int r0 = tid >> 3;                   // row within 64-row round
  const int pp = (tid & 7) ^ (r0 & 7);       // swizzled 16B chunk within 128B row
  const size_t offA = (size_t)r0 * lda + pp * 8;
  const size_t offB = (size_t)r0 * ldb + pp * 8;
  char* smw = sm + w * 1024;                 // wave-uniform LDS base (round 0)

  // stage-target base pointers for virtual tile v (K==1024 -> NT=16)
  auto baseA = [&](int v) -> const u16* {
    int tM, tN; tileOf(v >> 4, tM, tN);
    return A + (size_t)tM * lda + offA + ((v & 15) << 6);
  };
  auto baseB = [&](int v) -> const u16* {
    int tM, tN; tileOf(v >> 4, tM, tN);
    const u16* b = Bt0;
    if (MODE == 2) b += (size_t)(tM / rows_per_batch) * bstride;
    return b + (size_t)tN * ldb + offB + ((v & 15) << 6);
  };

  // ---- ds_read addressing (swizzled) ----
  const int cl = lane & 15, q = lane >> 4;
  int roA[8], roB[4];
#pragma unroll
  for (int mi = 0; mi < 8; ++mi) roA[mi] = (wm * 128 + mi * 16 + cl) * 128;
#pragma unroll
  for (int ni = 0; ni < 4; ++ni) roB[ni] = (wn * 64 + ni * 16 + cl) * 128;
  const int ck0 = ((0 + q) ^ (cl & 7)) * 16;
  const int ck1 = ((4 + q) ^ (cl & 7)) * 16;

  f32x4 acc[8][4];
#pragma unroll
  for (int i = 0; i < 8; ++i)
#pragma unroll
    for (int j2 = 0; j2 < 4; ++j2) acc[i][j2] = (f32x4){0.f, 0.f, 0.f, 0.f};

  bf16x8 ra[4][2], rb0[2][2], rb1[2][2];

#define FENCE asm volatile("" ::: "memory")
#define STGA(bufb, h, bp) do {                                                   \
    gll16((bp) + (size_t)(h) * 128 * lda, smw + (bufb) + (h) * 16384);           \
    gll16((bp) + ((size_t)(h) * 128 + 64) * lda, smw + (bufb) + (h) * 16384 + 8192); \
  } while (0)
#define STGB(bufb, h, bp) do {                                                   \
    gll16((bp) + (size_t)(h) * 128 * ldb, smw + (bufb) + 32768 + (h) * 16384);   \
    gll16((bp) + ((size_t)(h) * 128 + 64) * ldb, smw + (bufb) + 32768 + (h) * 16384 + 8192); \
  } while (0)

  const int NVT = CN * 16;   // K==1024 -> 16 K-tiles per assignment

  // ---- prologue: vtile0 {A0,B0,A1,B1}; vtile1 {A0,B0,A1} ----
  {
    const u16* a0 = baseA(0); const u16* b0 = baseB(0);
    STGA(0, 0, a0); STGB(0, 0, b0); STGA(0, 1, a0); STGB(0, 1, b0);
    const u16* a1 = baseA(1); const u16* b1 = baseB(1);
    STGA(65536, 0, a1); STGB(65536, 0, b1); STGA(65536, 1, a1);
    asm volatile("s_waitcnt vmcnt(6)" ::: "memory");   // vtile0 fully landed
  }
  FENCE; __builtin_amdgcn_s_barrier(); FENCE;

  for (int v = 0; v < NVT; ++v) {
    const int bufb  = (v & 1) << 16;
    const int nbufb = bufb ^ 65536;
    const char* sA = sm + bufb;
    const char* sB = sm + bufb + 32768;

    // ---- region 1: reads A-lo + B0; stage B1(v+1)->nbuf; q1; reads B1; q2 ----
#pragma unroll
    for (int mi = 0; mi < 4; ++mi) {
      ra[mi][0] = *(const bf16x8*)(sA + roA[mi] + ck0);
      ra[mi][1] = *(const bf16x8*)(sA + roA[mi] + ck1);
    }
#pragma unroll
    for (int ni = 0; ni < 2; ++ni) {
      rb0[ni][0] = *(const bf16x8*)(sB + roB[ni] + ck0);
      rb0[ni][1] = *(const bf16x8*)(sB + roB[ni] + ck1);
    }
    if (v + 1 < NVT) { const u16* bb = baseB(v + 1); STGB(nbufb, 1, bb); }
    __builtin_amdgcn_s_setprio(1);
#pragma unroll
    for (int mi = 0; mi < 4; ++mi)
#pragma unroll
      for (int ni = 0; ni < 2; ++ni) {
        acc[mi][ni] = __builtin_amdgcn_mfma_f32_16x16x32_bf16(ra[mi][0], rb0[ni][0], acc[mi][ni], 0, 0, 0);
        acc[mi][ni] = __builtin_amdgcn_mfma_f32_16x16x32_bf16(ra[mi][1], rb0[ni][1], acc[mi][ni], 0, 0, 0);
      }
    // rb1 reads placed after q1: q1's MFMAs cover their LDS latency
#pragma unroll
    for (int ni = 0; ni < 2; ++ni) {
      rb1[ni][0] = *(const bf16x8*)(sB + roB[2 + ni] + ck0);
      rb1[ni][1] = *(const bf16x8*)(sB + roB[2 + ni] + ck1);
    }
#pragma unroll
    for (int mi = 0; mi < 4; ++mi)
#pragma unroll
      for (int ni = 0; ni < 2; ++ni) {
        acc[mi][2 + ni] = __builtin_amdgcn_mfma_f32_16x16x32_bf16(ra[mi][0], rb1[ni][0], acc[mi][2 + ni], 0, 0, 0);
        acc[mi][2 + ni] = __builtin_amdgcn_mfma_f32_16x16x32_bf16(ra[mi][1], rb1[ni][1], acc[mi][2 + ni], 0, 0, 0);
      }
    __builtin_amdgcn_s_setprio(0);
    // every wave consumed rb0/rb1 -> all B reads of cur buf drained
    FENCE; __builtin_amdgcn_s_barrier(); FENCE;

    // ---- region 2: reads A-hi (overwrite ra); stage B0(v+2)->cur (B safe); q3 ----
#pragma unroll
    for (int mi = 0; mi < 4; ++mi) {
      ra[mi][0] = *(const bf16x8*)(sA + roA[4 + mi] + ck0);
      ra[mi][1] = *(const bf16x8*)(sA + roA[4 + mi] + ck1);
    }
    if (v + 2 < NVT) { const u16* bb2 = baseB(v + 2); STGB(bufb, 0, bb2); }
    __builtin_amdgcn_s_setprio(1);
#pragma unroll
    for (int mi = 0; mi < 4; ++mi)
#pragma unroll
      for (int ni = 0; ni < 2; ++ni) {
        acc[4 + mi][2 + ni] = __builtin_amdgcn_mfma_f32_16x16x32_bf16(ra[mi][0], rb1[ni][0], acc[4 + mi][2 + ni], 0, 0, 0);
        acc[4 + mi][2 + ni] = __builtin_amdgcn_mfma_f32_16x16x32_bf16(ra[mi][1], rb1[ni][1], acc[4 + mi][2 + ni], 0, 0, 0);
      }
    __builtin_amdgcn_s_setprio(0);
    // all A reads of cur buf drained
    FENCE; __builtin_amdgcn_s_barrier(); FENCE;

    // ---- region 3: stage A0+A1(v+2)->cur (A safe); q4 (pure-register); boundary ----
    if (v + 2 < NVT) {
      const u16* aa2 = baseA(v + 2);
      STGA(bufb, 0, aa2);
      STGA(bufb, 1, aa2);
    }
    __builtin_amdgcn_s_setprio(1);
#pragma unroll
    for (int mi = 0; mi < 4; ++mi)
#pragma unroll
      for (int ni = 0; ni < 2; ++ni) {
        acc[4 + mi][ni] = __builtin_amdgcn_mfma_f32_16x16x32_bf16(ra[mi][0], rb0[ni][0], acc[4 + mi][ni], 0, 0, 0);
        acc[4 + mi][ni] = __builtin_amdgcn_mfma_f32_16x16x32_bf16(ra[mi][1], rb0[ni][1], acc[4 + mi][ni], 0, 0, 0);
      }
    __builtin_amdgcn_s_setprio(0);
    if (v + 2 < NVT) asm volatile("s_waitcnt vmcnt(6)" ::: "memory");  // vtile v+1 landed
    else             asm volatile("s_waitcnt vmcnt(0)" ::: "memory");  // tail drain
    FENCE; __builtin_amdgcn_s_barrier(); FENCE;

    // ---------------- per-assignment epilogue (overlaps next stages) ----------------
    if ((v & 15) == 15) {
      int tM, tN; tileOf(v >> 4, tM, tN);
      const int colBase = tN + wn * 64;
      const int rowBase = tM + wm * 128;

      if (MODE == 1) {
        if (colBase < 1024) {
          // Q: softmax over the 64-col head chunk (no max-sub: |logit| < ~4), *SCALE
#pragma unroll
          for (int mi = 0; mi < 8; ++mi) {
#pragma unroll
            for (int r = 0; r < 4; ++r) {
              float e0 = __expf(acc[mi][0][r]), e1 = __expf(acc[mi][1][r]);
              float e2 = __expf(acc[mi][2][r]), e3 = __expf(acc[mi][3][r]);
              float s = (e0 + e1) + (e2 + e3);
              s += __shfl_xor(s, 1); s += __shfl_xor(s, 2);
              s += __shfl_xor(s, 4); s += __shfl_xor(s, 8);
              float inv = 0.125f / s;   // SCALE = DH^-0.5
              int row = rowBase + mi * 16 + q * 4 + r;
              u32x2 pv = { pk2(e0 * inv, e1 * inv), pk2(e2 * inv, e3 * inv) };
              __builtin_nontemporal_store(pv, (u32x2*)(Lout + (size_t)row * ldc + colBase + cl * 4));
            }
          }
        } else if (colBase < 2048) {
          // K: exp, packed store, accumulate column sums Z
          float zp0 = 0.f, zp1 = 0.f, zp2 = 0.f, zp3 = 0.f;
          const int b = tM / rows_per_batch;
#pragma unroll
          for (int mi = 0; mi < 8; ++mi) {
#pragma unroll
            for (int r = 0; r < 4; ++r) {
              float e0 = __expf(acc[mi][0][r]), e1 = __expf(acc[mi][1][r]);
              float e2 = __expf(acc[mi][2][r]), e3 = __expf(acc[mi][3][r]);
              zp0 += e0; zp1 += e1; zp2 += e2; zp3 += e3;
              int row = rowBase + mi * 16 + q * 4 + r;
              u32x2 pv = { pk2(e0, e1), pk2(e2, e3) };
              __builtin_nontemporal_store(pv, (u32x2*)(Lout + (size_t)row * ldc + colBase + cl * 4));
            }
          }
          float zp[4] = { zp0, zp1, zp2, zp3 };
#pragma unroll
          for (int ni = 0; ni < 4; ++ni) {
            float z = zp[ni];
            z += __shfl_xor(z, 16);
            z += __shfl_xor(z, 32);
            if (q == 0) atomicAdd(&Zp[b * 1024 + (colBase - 1024) + cl * 4 + ni], z);
          }
        } else {
          // V: packed bf16 store
#pragma unroll
          for (int mi = 0; mi < 8; ++mi) {
#pragma unroll
            for (int r = 0; r < 4; ++r) {
              int row = rowBase + mi * 16 + q * 4 + r;
              u32x2 pv = { pk2(acc[mi][0][r], acc[mi][1][r]),
                           pk2(acc[mi][2][r], acc[mi][3][r]) };
              __builtin_nontemporal_store(pv, (u32x2*)(Lout + (size_t)row * ldc + colBase + cl * 4));
            }
          }
        }
      } else {
        // MODE 2: f32 + bias, nontemporal float4 stores
        const float4 bb = *(const float4*)(bias + colBase + cl * 4);
#pragma unroll
        for (int mi = 0; mi < 8; ++mi) {
#pragma unroll
          for (int r = 0; r < 4; ++r) {
            int row = rowBase + mi * 16 + q * 4 + r;
            f32x4 vv = { acc[mi][0][r] + bb.x, acc[mi][1][r] + bb.y,
                         acc[mi][2][r] + bb.z, acc[mi][3][r] + bb.w };
            __builtin_nontemporal_store(vv, (f32x4*)(Fout + (size_t)row * ldc + colBase + cl * 4));
          }
        }
      }
      // reset accumulators for the next assignment
#pragma unroll
      for (int i = 0; i < 8; ++i)
#pragma unroll
        for (int j2 = 0; j2 < 4; ++j2) acc[i][j2] = (f32x4){0.f, 0.f, 0.f, 0.f};
    }
  }
#undef STGA
#undef STGB
#undef FENCE
}

// ---------------------------------------------------------------------------
// ctx partials via MFMA: part[bh][wslot][d][pe] = sum_{s in slot} expK[s,d]*V[s,e]
// L reads single-use -> nontemporal (also protects Q-part residency for GEMM2).
__global__ __launch_bounds__(256) void ctx_mfma(const u16* __restrict__ L,
                                                float* __restrict__ part) {
  __shared__ __align__(16) u16 kvt[4][2][64 * 40];   // [wave][K/V][d][s], stride 40
  const int bh = blockIdx.y, b = bh >> 4, h = bh & 15;
  const int lane = threadIdx.x & 63, w = threadIdx.x >> 6;
  u16* kt = &kvt[w][0][0];
  u16* vt = &kvt[w][1][0];
  const int sl = lane & 31, half = lane >> 5;
  const int cl = lane & 15, q = lane >> 4;

  f32x4 acc[4][4];
#pragma unroll
  for (int i = 0; i < 4; ++i)
#pragma unroll
    for (int j = 0; j < 4; ++j) acc[i][j] = (f32x4){0.f, 0.f, 0.f, 0.f};

  const int sbase0 = blockIdx.x * 1024 + w * 256;
  for (int c = 0; c < 8; ++c) {
    const size_t rowb = ((size_t)b * 8192 + sbase0 + c * 32 + sl) * 3072;
#pragma unroll
    for (int dblk = 0; dblk < 4; ++dblk) {
      int d0 = dblk * 16 + half * 8;
      u16x8 kv = __builtin_nontemporal_load((const u16x8*)(L + rowb + 1024 + h * 64 + d0));
      u16x8 vv = __builtin_nontemporal_load((const u16x8*)(L + rowb + 2048 + h * 64 + d0));
#pragma unroll
      for (int j = 0; j < 8; ++j) {
        kt[(d0 + j) * 40 + sl] = kv[j];
        vt[(d0 + j) * 40 + sl] = vv[j];
      }
    }
    bf16x8 af[4], bfr[4];
#pragma unroll
    for (int mi = 0; mi < 4; ++mi) af[mi]  = *(const bf16x8*)&kt[(mi * 16 + cl) * 40 + q * 8];
#pragma unroll
    for (int ni = 0; ni < 4; ++ni) bfr[ni] = *(const bf16x8*)&vt[(ni * 16 + cl) * 40 + q * 8];
#pragma unroll
    for (int mi = 0; mi < 4; ++mi)
#pragma unroll
      for (int ni = 0; ni < 4; ++ni)
        acc[mi][ni] = __builtin_amdgcn_mfma_f32_16x16x32_bf16(af[mi], bfr[ni], acc[mi][ni], 0, 0, 0);
  }

  const int wslot = blockIdx.x * 4 + w;
  float* pb = part + ((size_t)bh * 32 + wslot) * 4096;
#pragma unroll
  for (int mi = 0; mi < 4; ++mi)
#pragma unroll
    for (int r = 0; r < 4; ++r) {
      float4 v = { acc[mi][0][r], acc[mi][1][r], acc[mi][2][r], acc[mi][3][r] };
      *(float4*)(pb + (mi * 16 + q * 4 + r) * 64 + cl * 4) = v;
    }
}

// cn[bh][d][pe] = (sum_w part[bh][w][d][pe]) / Z[b*1024 + h*64 + d]
__global__ __launch_bounds__(256) void norm_ctx(const float* __restrict__ part,
                                                const float* __restrict__ Z,
                                                float* __restrict__ cn) {
  int i = blockIdx.x * 256 + threadIdx.x;   // 262144
  int bh = i >> 12, rest = i & 4095, d = rest >> 6;
  float s = 0.f;
#pragma unroll
  for (int w = 0; w < 32; ++w) s += part[((size_t)bh * 32 + w) * 4096 + rest];
  cn[i] = s / Z[(bh >> 4) * 1024 + (bh & 15) * 64 + d];
}

// Weff_t[b][p][h*64+d] = sum_pe cn[bh][d][pe] * Wlin[(h*64+e(pe))*1024 + lam(p)]
__global__ __launch_bounds__(256) void weff_k(const float* __restrict__ cn,
                                              const float* __restrict__ Wlin,
                                              u16* __restrict__ Wt) {
  int bh = blockIdx.y; int b = bh >> 4, h = bh & 15;
  int p = blockIdx.x * 256 + threadIdx.x;
  int up = p & 63;
  int j = (p & ~63) | ((up & 15) << 2) | (up >> 4);   // logical out col
  const float* c = cn + (size_t)bh * 4096;
  float out[64];
#pragma unroll
  for (int d = 0; d < 64; ++d) out[d] = 0.f;
  for (int pe = 0; pe < 64; ++pe) {
    int e = ((pe & 3) << 4) | (pe >> 2);              // logical e at stored pos pe
    float wv = Wlin[(size_t)(h * 64 + e) * 1024 + j];
#pragma unroll
    for (int d = 0; d < 64; ++d) out[d] += c[d * 64 + pe] * wv;
  }
  u16* dst = Wt + ((size_t)b * 1024 + p) * 1024 + h * 64;
#pragma unroll
  for (int d0 = 0; d0 < 64; d0 += 2)
    *(u32*)(dst + d0) = pk2(out[d0], out[d0 + 1]);
}

// ---------------------------------------------------------------------------
extern "C" void kernel_launch(void* const* d_in, const int* in_sizes, int n_in,
                              void* d_out, int out_size, void* d_ws, size_t ws_size,
                              hipStream_t stream) {
  const float* x    = (const float*)d_in[0];
  const float* Wq   = (const float*)d_in[1];
  const float* Wkv  = (const float*)d_in[2];
  const float* Wlin = (const float*)d_in[3];
  const float* blin = (const float*)d_in[4];
  float* out = (float*)d_out;
  char* ws = (char*)d_ws;

  // phase-1 workspace
  u16*   xb   = (u16*)(ws);                    // 64 MB : x bf16 (32768 x 1024)
  u16*   w3t  = (u16*)(ws + 67108864);         // 6 MB  : W3^T bf16 (3072 x 1024), permuted
  u16*   L    = (u16*)(ws + 73400320);         // 192 MB: [Qs | expK | V] bf16 (32768 x 3072)
  float* Zp   = (float*)(ws + 274726912);      // 16 KB : K-softmax denominators (4 x 1024)
  // phase-2 workspace (reuses xb region; xb is dead after GEMM1)
  float* part = (float*)(ws);                  // 32 MB : ctx partials (64 x 32 x 64 x 64)
  float* cn   = (float*)(ws + 33554432);       // 1 MB  : ctx normalized (permuted e)
  u16*   weff = (u16*)(ws + 34603008);         // 8 MB  : Weff^T bf16 (4 x 1024 x 1024), permuted rows

  hipMemsetAsync(Zp, 0, 16384, stream);

  cvt_x<<<32768, 256, 0, stream>>>(x, xb, 33554432);
  build_w3t<<<dim3(96, 32), 256, 0, stream>>>(Wq, Wkv, w3t);

  // persistent: 256 blocks x 6 assignments (12 x 128 tiles)
  gemm_bt_k<1, 6><<<256, 512, 0, stream>>>(
      xb, 1024, w3t, 1024, 1024, L, 3072, nullptr, Zp, nullptr, (size_t)0, 8192);

  ctx_mfma<<<dim3(8, 64), 256, 0, stream>>>(L, part);
  norm_ctx<<<1024, 256, 0, stream>>>(part, Zp, cn);
  weff_k<<<dim3(4, 64), 256, 0, stream>>>(cn, Wlin, weff);

  // persistent: 256 blocks x 2 assignments (4 x 128 tiles)
  gemm_bt_k<2, 2><<<256, 512, 0, stream>>>(
      L, 3072, weff, 1024, 1024, nullptr, 1024, out, nullptr, blin, (size_t)1048576, 8192);
}